// Round 2
// baseline (1950.665 us; speedup 1.0000x reference)
//
#include <hip/hip_runtime.h>
#include <hip/hip_bf16.h>
#include <math.h>

// Problem constants
#define BB 8
#define KK 4
#define LL 1024
#define DD 512
#define HH 8
#define HD 64
#define D3 1536
#define MM (BB*LL*KK)   // 32768 rows for per-state GEMMs
#define BL (BB*LL)      // 8192 (b,l) positions
#define SCALE 0.125f    // 64^-0.5
#define EPSF 1e-8f
#define LN_EPSF 1e-5f

// ---------------------------------------------------------------------------
// nsw: per (b,k) normalized state weights.  Masks arrive as int32 (harness
// widens numpy bool to int).
__global__ void nsw_kernel(const float* __restrict__ sw,
                           const int* __restrict__ pres,
                           float* __restrict__ nsw_ws, float* __restrict__ nsw_out) {
    int b = threadIdx.x;
    if (b < BB) {
        float w[KK]; float denom = 0.f, ps = 0.f;
        for (int k = 0; k < KK; ++k) {
            float p = pres[b*KK + k] ? 1.f : 0.f;
            w[k] = sw[b*KK + k] * p;
            denom += w[k]; ps += p;
        }
        for (int k = 0; k < KK; ++k) {
            float val;
            if (denom > EPSF) val = w[k] / fmaxf(denom, EPSF);
            else              val = (pres[b*KK + k] ? 1.f : 0.f) / fmaxf(ps, 1.f);
            nsw_ws[b*KK + k] = val;
            nsw_out[b*KK + k] = val;
        }
    }
}

// ---------------------------------------------------------------------------
// Build x[(b,l,k),d] = (state_repr[b,k,l,d] + role_emb[role]) * valid, and
// rowmask[m] = valid as float.
__global__ __launch_bounds__(256) void buildx_kernel(
        const float* __restrict__ SR, const int* __restrict__ residue,
        const int* __restrict__ pres, const int* __restrict__ roles,
        const float* __restrict__ role_emb, float* __restrict__ X,
        float* __restrict__ rowmask) {
    int t = blockIdx.x * 256 + threadIdx.x;       // one float4 per thread
    int m  = t >> 7;                               // 128 float4 per row
    int q4 = t & 127;
    int ks = m & 3;
    int bl = m >> 2;
    int b  = bl >> 10;
    int l  = bl & 1023;
    int bk = b*KK + ks;
    bool valid = (residue[(size_t)bk*LL + l] != 0) && (pres[bk] != 0);
    float vf = valid ? 1.f : 0.f;
    int role = roles[bk]; if (role < 0) role = 0;
    const float4 sr = *(const float4*)(SR + ((size_t)bk*LL + l)*DD + q4*4);
    const float4 re = *(const float4*)(role_emb + (size_t)role*DD + q4*4);
    float4 o;
    o.x = (sr.x + re.x) * vf;
    o.y = (sr.y + re.y) * vf;
    o.z = (sr.z + re.z) * vf;
    o.w = (sr.w + re.w) * vf;
    *(float4*)(X + (size_t)m*DD + q4*4) = o;
    if (q4 == 0) rowmask[m] = vf;
}

// ---------------------------------------------------------------------------
// Tiled fp32 GEMM: C[M,N] = A[M,Kd] @ W[N,Kd]^T (+ epilogue)
// EPI: 0=none, 1=mul rowmask[m], 2=bias+gelu(exact), 3=bias+sigmoid
template<int EPI>
__global__ __launch_bounds__(256) void gemm_nt(
        const float* __restrict__ A, const float* __restrict__ W,
        float* __restrict__ C, int M, int N, int Kd,
        const float* __restrict__ bias, const float* __restrict__ rowmask) {
    __shared__ float As[64][17];
    __shared__ float Bs[64][17];
    const int tid = threadIdx.x;
    const int tx = tid & 15, ty = tid >> 4;
    const int m0 = blockIdx.y * 64, n0 = blockIdx.x * 64;
    const int lrow = tid >> 2, lquad = tid & 3;
    const float* Arow = A + (size_t)(m0 + lrow) * Kd + lquad*4;
    const float* Wrow = W + (size_t)(n0 + lrow) * Kd + lquad*4;
    float acc[4][4] = {};
    for (int k0 = 0; k0 < Kd; k0 += 16) {
        float4 av = *(const float4*)(Arow + k0);
        float4 wv = *(const float4*)(Wrow + k0);
        As[lrow][lquad*4+0] = av.x; As[lrow][lquad*4+1] = av.y;
        As[lrow][lquad*4+2] = av.z; As[lrow][lquad*4+3] = av.w;
        Bs[lrow][lquad*4+0] = wv.x; Bs[lrow][lquad*4+1] = wv.y;
        Bs[lrow][lquad*4+2] = wv.z; Bs[lrow][lquad*4+3] = wv.w;
        __syncthreads();
        #pragma unroll
        for (int kk = 0; kk < 16; ++kk) {
            float a[4], bb[4];
            #pragma unroll
            for (int i = 0; i < 4; ++i) a[i] = As[ty*4+i][kk];
            #pragma unroll
            for (int j = 0; j < 4; ++j) bb[j] = Bs[tx*4+j][kk];
            #pragma unroll
            for (int i = 0; i < 4; ++i)
                #pragma unroll
                for (int j = 0; j < 4; ++j)
                    acc[i][j] = fmaf(a[i], bb[j], acc[i][j]);
        }
        __syncthreads();
    }
    #pragma unroll
    for (int i = 0; i < 4; ++i) {
        int m = m0 + ty*4 + i;
        float rmv = (EPI == 1) ? rowmask[m] : 1.f;
        #pragma unroll
        for (int j = 0; j < 4; ++j) {
            int n = n0 + tx*4 + j;
            float v = acc[i][j];
            if (EPI == 1) v *= rmv;
            if (EPI == 2) { v += bias[n]; v = 0.5f * v * (1.f + erff(v * 0.70710678118654752f)); }
            if (EPI == 3) { v += bias[n]; v = 1.f / (1.f + expf(-v)); }
            C[(size_t)m * N + n] = v;
        }
    }
}

// ---------------------------------------------------------------------------
// Per-(b,l) attention over K=4 states. Writes attn_out over the Q buffer,
// and attn_mean to d_out.
__global__ __launch_bounds__(256) void attn_kernel(
        float* Qb /* in: q, out: attn_out (same buffer) */,
        const float* __restrict__ Kb, const float* __restrict__ Vb,
        const float* __restrict__ nsw, const float* __restrict__ rowmask,
        float* __restrict__ attn_mean_out) {
    __shared__ float qs[KK][DD];
    __shared__ float ks[KK][DD];
    __shared__ float vs[KK][DD];
    __shared__ float att[128];           // [h][i][j] = h*16 + i*4 + j
    __shared__ float lw[KK], mk[KK];
    int bl = blockIdx.x;
    int b  = bl >> 10;
    int mb = bl * KK;
    int tid = threadIdx.x;
    for (int p = 0; p < 8; ++p) {
        int idx = p*256 + tid;
        int k = idx >> 9, d = idx & 511;
        qs[k][d] = Qb[(size_t)(mb+k)*DD + d];
        ks[k][d] = Kb[(size_t)(mb+k)*DD + d];
        vs[k][d] = Vb[(size_t)(mb+k)*DD + d];
    }
    if (tid < KK) {
        lw[tid] = logf(fmaxf(nsw[b*KK + tid], EPSF));
        mk[tid] = rowmask[mb + tid];
    }
    __syncthreads();
    if (tid < 128) {
        int h = tid >> 4, i = (tid >> 2) & 3, j = tid & 3;
        float s = 0.f;
        #pragma unroll 16
        for (int d = 0; d < HD; ++d) s = fmaf(qs[i][h*HD + d], ks[j][h*HD + d], s);
        float lg = s * SCALE + lw[j];
        att[tid] = (mk[j] > 0.5f) ? lg : -INFINITY;
    }
    __syncthreads();
    if (tid < 32) {
        int base = tid * 4;
        float l0 = att[base], l1 = att[base+1], l2 = att[base+2], l3 = att[base+3];
        float m = fmaxf(fmaxf(l0, l1), fmaxf(l2, l3));
        if (m == -INFINITY) {
            att[base] = att[base+1] = att[base+2] = att[base+3] = 0.f;
        } else {
            float e0 = expf(l0 - m), e1 = expf(l1 - m), e2 = expf(l2 - m), e3 = expf(l3 - m);
            float inv = 1.f / (e0 + e1 + e2 + e3);
            att[base] = e0*inv; att[base+1] = e1*inv; att[base+2] = e2*inv; att[base+3] = e3*inv;
        }
    }
    __syncthreads();
    if (tid < KK) {
        float s = 0.f;
        for (int hi = 0; hi < 32; ++hi) s += att[hi*4 + tid];
        attn_mean_out[(size_t)bl*KK + tid] = s * (1.f/32.f);
    }
    float outv[8];
    #pragma unroll
    for (int p = 0; p < 8; ++p) {
        int idx = p*256 + tid;
        int i = idx >> 9, dc = idx & 511, h = dc >> 6;
        float s = 0.f;
        #pragma unroll
        for (int j = 0; j < KK; ++j) s = fmaf(att[h*16 + i*4 + j], vs[j][dc], s);
        outv[p] = s;
    }
    #pragma unroll
    for (int p = 0; p < 8; ++p) {
        int idx = p*256 + tid;
        int i = idx >> 9, dc = idx & 511;
        Qb[(size_t)(mb+i)*DD + dc] = outv[p];
    }
}

// ---------------------------------------------------------------------------
__device__ __forceinline__ void block_reduce2(float& a, float& b, float* lds) {
    #pragma unroll
    for (int o = 32; o > 0; o >>= 1) {
        a += __shfl_down(a, o, 64);
        b += __shfl_down(b, o, 64);
    }
    int wave = threadIdx.x >> 6, lane = threadIdx.x & 63;
    if (lane == 0) { lds[wave*2] = a; lds[wave*2+1] = b; }
    __syncthreads();
    if (threadIdx.x == 0) {
        float sa = 0.f, sb = 0.f;
        for (int w = 0; w < 4; ++w) { sa += lds[2*w]; sb += lds[2*w+1]; }
        lds[0] = sa; lds[1] = sb;
    }
    __syncthreads();
    a = lds[0]; b = lds[1];
    __syncthreads();
}

// Pooling + LN over gate_in; writes attn_pooled/weighted_mean/max_feat outputs
// and the LN1-normalized gate_in (B,L,1536) for the MLP.
__global__ __launch_bounds__(256) void pool_kernel(
        const float* __restrict__ X, const float* __restrict__ AOP,
        const float* __restrict__ nsw, const float* __restrict__ rowmask,
        const float* __restrict__ ln1_g, const float* __restrict__ ln1_b,
        float* __restrict__ out_ap, float* __restrict__ out_wm,
        float* __restrict__ out_mx, float* __restrict__ hin) {
    __shared__ float red[16];
    int bl = blockIdx.x;
    int b = bl >> 10;
    int mb = bl * KK;
    int tid = threadIdx.x;
    float mkv[KK], swr[KK];
    float ssum = 0.f, many = 0.f;
    #pragma unroll
    for (int k = 0; k < KK; ++k) {
        mkv[k] = rowmask[mb + k];
        swr[k] = nsw[b*KK + k] * mkv[k];
        ssum += swr[k]; many += mkv[k];
    }
    float inv = 1.f / fmaxf(ssum, EPSF);
    #pragma unroll
    for (int k = 0; k < KK; ++k) swr[k] *= inv;
    bool hasany = many > 0.5f;
    float apv[2], wmv[2], mxv[2];
    float lsum = 0.f, lsq = 0.f;
    #pragma unroll
    for (int it = 0; it < 2; ++it) {
        int d = tid + it*256;
        float wm = 0.f, ap = 0.f, mx = -1e9f;
        #pragma unroll
        for (int k = 0; k < KK; ++k) {
            float xv = X[(size_t)(mb+k)*DD + d];
            float av = AOP[(size_t)(mb+k)*DD + d];
            wm = fmaf(xv, swr[k], wm);
            ap = fmaf(av, swr[k], ap);
            if (mkv[k] > 0.5f) mx = fmaxf(mx, xv);
        }
        if (!hasany) mx = 0.f;
        apv[it] = ap; wmv[it] = wm; mxv[it] = mx;
        lsum += ap + wm + mx;
        lsq  += ap*ap + wm*wm + mx*mx;
    }
    block_reduce2(lsum, lsq, red);
    float mu = lsum * (1.f/(float)D3);
    float var = lsq * (1.f/(float)D3) - mu*mu;
    float rstd = rsqrtf(var + LN_EPSF);
    #pragma unroll
    for (int it = 0; it < 2; ++it) {
        int d = tid + it*256;
        out_ap[(size_t)bl*DD + d] = apv[it];
        out_wm[(size_t)bl*DD + d] = wmv[it];
        out_mx[(size_t)bl*DD + d] = mxv[it];
        hin[(size_t)bl*D3 + d]        = (apv[it]-mu)*rstd*ln1_g[d]        + ln1_b[d];
        hin[(size_t)bl*D3 + 512 + d]  = (wmv[it]-mu)*rstd*ln1_g[512 + d]  + ln1_b[512 + d];
        hin[(size_t)bl*D3 + 1024 + d] = (mxv[it]-mu)*rstd*ln1_g[1024 + d] + ln1_b[1024 + d];
    }
}

// ---------------------------------------------------------------------------
// fused = LN(gate*fusion_base + (1-gate)*max_feat + weighted_mean)
__global__ __launch_bounds__(256) void final_kernel(
        const float* __restrict__ out_ap, const float* __restrict__ out_wm,
        const float* __restrict__ out_mx, const float* __restrict__ gate,
        const float* __restrict__ norm_g, const float* __restrict__ norm_b,
        float* __restrict__ fused) {
    __shared__ float red[16];
    int bl = blockIdx.x;
    int tid = threadIdx.x;
    float pre[2];
    float lsum = 0.f, lsq = 0.f;
    #pragma unroll
    for (int it = 0; it < 2; ++it) {
        int d = tid + it*256;
        float ap = out_ap[(size_t)bl*DD + d];
        float wm = out_wm[(size_t)bl*DD + d];
        float mx = out_mx[(size_t)bl*DD + d];
        float g  = gate[(size_t)bl*DD + d];
        float fb = 0.5f * (ap + wm);
        float p = g*fb + (1.f-g)*mx + wm;
        pre[it] = p;
        lsum += p; lsq += p*p;
    }
    block_reduce2(lsum, lsq, red);
    float mu = lsum * (1.f/(float)DD);
    float var = lsq * (1.f/(float)DD) - mu*mu;
    float rstd = rsqrtf(var + LN_EPSF);
    #pragma unroll
    for (int it = 0; it < 2; ++it) {
        int d = tid + it*256;
        fused[(size_t)bl*DD + d] = (pre[it]-mu)*rstd*norm_g[d] + norm_b[d];
    }
}

// ---------------------------------------------------------------------------
extern "C" void kernel_launch(void* const* d_in, const int* in_sizes, int n_in,
                              void* d_out, int out_size, void* d_ws, size_t ws_size,
                              hipStream_t stream) {
    const float* SR      = (const float*)d_in[0];
    const int*   residue = (const int*)d_in[1];      // bool -> int32 (harness)
    const float* sw      = (const float*)d_in[2];
    const int*   roles   = (const int*)d_in[3];
    const int*   pres    = (const int*)d_in[4];      // bool -> int32 (harness)
    const float* role_emb= (const float*)d_in[5];
    const float* Wq      = (const float*)d_in[6];
    const float* Wk      = (const float*)d_in[7];
    const float* Wv      = (const float*)d_in[8];
    const float* Wo      = (const float*)d_in[9];
    const float* ln1_g   = (const float*)d_in[10];
    const float* ln1_b   = (const float*)d_in[11];
    const float* Wg1     = (const float*)d_in[12];
    const float* bg1     = (const float*)d_in[13];
    const float* Wg2     = (const float*)d_in[14];
    const float* bg2     = (const float*)d_in[15];
    const float* norm_g  = (const float*)d_in[16];
    const float* norm_b  = (const float*)d_in[17];

    float* out = (float*)d_out;
    const size_t BLD = (size_t)BL * DD;           // 4194304
    float* f_fused = out;
    float* f_ap    = out + BLD;
    float* f_wm    = out + 2*BLD;
    float* f_mx    = out + 3*BLD;
    float* f_am    = out + 4*BLD;                 // (B,L,K)
    float* f_nsw   = out + 4*BLD + (size_t)BL*KK; // (B,K)

    float* ws = (float*)d_ws;
    const size_t MD = (size_t)MM * DD;            // 16777216 floats
    float* Xb    = ws;
    float* Qb    = ws + MD;
    float* Kb    = ws + 2*MD;
    float* Vb    = ws + 3*MD;
    float* nsww  = ws + 4*MD;
    float* rmask = nsww + 32;
    float* Hin   = Vb;                 // (B,L,1536) after V is dead
    float* Hbuf  = Xb;                 // (B,L,512) after X is dead -- NOTE: X
                                       // is still needed by pool; Hbuf only
                                       // written after pool completes.
    float* Gate  = Xb + BLD;           // (B,L,512)

    dim3 blk(256);

    nsw_kernel<<<1, 64, 0, stream>>>(sw, pres, nsww, f_nsw);
    buildx_kernel<<<(MM*128)/256, blk, 0, stream>>>(SR, residue, pres, roles, role_emb, Xb, rmask);

    dim3 gBig(DD/64, MM/64);           // (8, 512)
    gemm_nt<0><<<gBig, blk, 0, stream>>>(Xb, Wq, Qb, MM, DD, DD, nullptr, nullptr);
    gemm_nt<0><<<gBig, blk, 0, stream>>>(Xb, Wk, Kb, MM, DD, DD, nullptr, nullptr);
    gemm_nt<0><<<gBig, blk, 0, stream>>>(Xb, Wv, Vb, MM, DD, DD, nullptr, nullptr);

    attn_kernel<<<BL, blk, 0, stream>>>(Qb, Kb, Vb, nsww, rmask, f_am);

    gemm_nt<1><<<gBig, blk, 0, stream>>>(Qb, Wo, Kb, MM, DD, DD, nullptr, rmask);

    pool_kernel<<<BL, blk, 0, stream>>>(Xb, Kb, nsww, rmask, ln1_g, ln1_b,
                                        f_ap, f_wm, f_mx, Hin);

    dim3 gMlp(DD/64, BL/64);           // (8, 128)
    gemm_nt<2><<<gMlp, blk, 0, stream>>>(Hin, Wg1, Hbuf, BL, DD, D3, bg1, nullptr);
    gemm_nt<3><<<gMlp, blk, 0, stream>>>(Hbuf, Wg2, Gate, BL, DD, DD, bg2, nullptr);

    final_kernel<<<BL, blk, 0, stream>>>(f_ap, f_wm, f_mx, Gate, norm_g, norm_b, f_fused);
}

// Round 3
// 436.677 us; speedup vs baseline: 4.4671x; 4.4671x over previous
//
#include <hip/hip_runtime.h>
#include <math.h>

// Problem constants
#define BB 8
#define KK 4
#define LL 1024
#define DD 512
#define HD 64
#define D3 1536
#define MM (BB*LL*KK)   // 32768 rows for per-state GEMMs
#define BL (BB*LL)      // 8192 (b,l) positions
#define SCALE 0.125f
#define EPSF 1e-8f
#define LN_EPSF 1e-5f

typedef _Float16 hfrag __attribute__((ext_vector_type(8)));
typedef float f32x4 __attribute__((ext_vector_type(4)));

__device__ __forceinline__ unsigned short f2h(float f) {
    _Float16 h = (_Float16)f;
    unsigned short u; __builtin_memcpy(&u, &h, 2); return u;
}
__device__ __forceinline__ float h2f(unsigned short u) {
    _Float16 h; __builtin_memcpy(&h, &u, 2); return (float)h;
}

__device__ __forceinline__ void glds16(const unsigned short* g, unsigned short* l) {
    __builtin_amdgcn_global_load_lds(
        (const __attribute__((address_space(1))) void*)g,
        (__attribute__((address_space(3))) void*)l, 16, 0, 0);
}

// ---------------------------------------------------------------------------
// Fused fp32 -> fp16 weight conversion (Wq|Wk|Wv|Wo|Wg1|Wg2 concatenated)
#define WSZ 262144          // 512*512
#define OG1 1048576         // start of Wg1 (512*1536)
#define OG2 1835008         // start of Wg2
#define WTOT 2097152
__global__ __launch_bounds__(256) void cvt_weights(
        const float* __restrict__ Wq, const float* __restrict__ Wk,
        const float* __restrict__ Wv, const float* __restrict__ Wo,
        const float* __restrict__ Wg1, const float* __restrict__ Wg2,
        unsigned short* __restrict__ dst) {
    int t = blockIdx.x * 256 + threadIdx.x;   // one float4 per thread
    int e = t * 4;
    const float* src; int off;
    if      (e < WSZ)    { src = Wq;  off = e; }
    else if (e < 2*WSZ)  { src = Wk;  off = e - WSZ; }
    else if (e < 3*WSZ)  { src = Wv;  off = e - 2*WSZ; }
    else if (e < OG1)    { src = Wo;  off = e - 3*WSZ; }
    else if (e < OG2)    { src = Wg1; off = e - OG1; }
    else                 { src = Wg2; off = e - OG2; }
    float4 v = *(const float4*)(src + off);
    ushort4 o;
    o.x = f2h(v.x); o.y = f2h(v.y); o.z = f2h(v.z); o.w = f2h(v.w);
    *(ushort4*)(dst + e) = o;
}

// ---------------------------------------------------------------------------
// nsw (masks arrive as int32: harness widens numpy bool)
__global__ void nsw_kernel(const float* __restrict__ sw,
                           const int* __restrict__ pres,
                           float* __restrict__ nsw_ws, float* __restrict__ nsw_out) {
    int b = threadIdx.x;
    if (b < BB) {
        float w[KK]; float denom = 0.f, ps = 0.f;
        for (int k = 0; k < KK; ++k) {
            float p = pres[b*KK + k] ? 1.f : 0.f;
            w[k] = sw[b*KK + k] * p;
            denom += w[k]; ps += p;
        }
        for (int k = 0; k < KK; ++k) {
            float val;
            if (denom > EPSF) val = w[k] / fmaxf(denom, EPSF);
            else              val = (pres[b*KK + k] ? 1.f : 0.f) / fmaxf(ps, 1.f);
            nsw_ws[b*KK + k] = val;
            nsw_out[b*KK + k] = val;
        }
    }
}

// ---------------------------------------------------------------------------
// Build x (fp16) + weighted_mean/max_feat (fp32, exact) + rowmask.
__global__ __launch_bounds__(256) void buildx_kernel(
        const float* __restrict__ SR, const int* __restrict__ residue,
        const int* __restrict__ pres, const int* __restrict__ roles,
        const float* __restrict__ role_emb, const float* __restrict__ nsw,
        unsigned short* __restrict__ Xh, float* __restrict__ rowmask,
        float* __restrict__ out_wm, float* __restrict__ out_mx) {
    int t  = blockIdx.x * 256 + threadIdx.x;
    int bl = t >> 7;
    int d4 = (t & 127) << 2;
    int b  = bl >> 10, l = bl & 1023;
    float mk[KK], swr[KK];
    float ssum = 0.f, many = 0.f;
    #pragma unroll
    for (int k = 0; k < KK; ++k) {
        int bk = b*KK + k;
        bool valid = (residue[(size_t)bk*LL + l] != 0) && (pres[bk] != 0);
        mk[k]  = valid ? 1.f : 0.f;
        swr[k] = nsw[bk] * mk[k];
        ssum += swr[k]; many += mk[k];
    }
    float inv = 1.f / fmaxf(ssum, EPSF);
    bool hasany = many > 0.5f;
    float wmx = 0.f, wmy = 0.f, wmz = 0.f, wmw = 0.f;
    float mxx = -1e9f, mxy = -1e9f, mxz = -1e9f, mxw = -1e9f;
    #pragma unroll
    for (int k = 0; k < KK; ++k) {
        int bk = b*KK + k;
        int role = roles[bk]; if (role < 0) role = 0;
        float4 sr = *(const float4*)(SR + ((size_t)bk*LL + l)*DD + d4);
        float4 re = *(const float4*)(role_emb + (size_t)role*DD + d4);
        float xx = (sr.x + re.x)*mk[k], xy = (sr.y + re.y)*mk[k];
        float xz = (sr.z + re.z)*mk[k], xw = (sr.w + re.w)*mk[k];
        ushort4 xs; xs.x = f2h(xx); xs.y = f2h(xy); xs.z = f2h(xz); xs.w = f2h(xw);
        *(ushort4*)(Xh + (size_t)(bl*KK + k)*DD + d4) = xs;
        float s = swr[k]*inv;
        wmx = fmaf(xx, s, wmx); wmy = fmaf(xy, s, wmy);
        wmz = fmaf(xz, s, wmz); wmw = fmaf(xw, s, wmw);
        if (mk[k] > 0.5f) {
            mxx = fmaxf(mxx, xx); mxy = fmaxf(mxy, xy);
            mxz = fmaxf(mxz, xz); mxw = fmaxf(mxw, xw);
        }
    }
    if (!hasany) { mxx = mxy = mxz = mxw = 0.f; }
    float4 wmv; wmv.x = wmx; wmv.y = wmy; wmv.z = wmz; wmv.w = wmw;
    float4 mxv; mxv.x = mxx; mxv.y = mxy; mxv.z = mxz; mxv.w = mxw;
    *(float4*)(out_wm + (size_t)bl*DD + d4) = wmv;
    *(float4*)(out_mx + (size_t)bl*DD + d4) = mxv;
    if (d4 == 0) {
        #pragma unroll
        for (int k = 0; k < KK; ++k) rowmask[bl*KK + k] = mk[k];
    }
}

// ---------------------------------------------------------------------------
// m97-style MFMA GEMM: C[M,N] = A[M,K] @ W[N,K]^T, fp16 in, fp32 accum.
// 128x128 tile, BK=32, 4 waves x (4x4) 16x16x32 MFMA fragments.
// EPI: 0=none, 1=*rowmask[m], 2=bias+gelu(exact), 3=bias+sigmoid
// OUTH: 1 = fp16 output, 0 = fp32 output
template<int EPI, int OUTH>
__global__ __launch_bounds__(256) void gemm_mfma(
        const unsigned short* __restrict__ A, const unsigned short* __restrict__ W,
        void* __restrict__ Cv, int M, int N, int Kd,
        const float* __restrict__ bias, const float* __restrict__ rowmask) {
    __shared__ __align__(16) unsigned short As[128*32];
    __shared__ __align__(16) unsigned short Bs[128*32];
    const int tid  = threadIdx.x;
    const int wave = tid >> 6, lane = tid & 63;
    const int m0 = blockIdx.y * 128, n0 = blockIdx.x * 128;
    const int srow = lane >> 2;          // 0..15
    const int scol = (lane & 3) << 3;    // 0,8,16,24
    const unsigned short* Ag0 = A + (size_t)(m0 + wave*32 + srow) * Kd + scol;
    const unsigned short* Ag1 = Ag0 + (size_t)16 * Kd;
    const unsigned short* Wp0 = W + (size_t)(n0 + wave*32 + srow) * Kd + scol;
    const unsigned short* Wp1 = Wp0 + (size_t)16 * Kd;
    unsigned short* Al0 = As + (wave*32 + srow)*32 + scol;  // HW uses lane0 base + lane*16B
    unsigned short* Al1 = Al0 + 16*32;
    unsigned short* Bl0 = Bs + (wave*32 + srow)*32 + scol;
    unsigned short* Bl1 = Bl0 + 16*32;
    const int wr = (wave >> 1) * 64;
    const int wc = (wave & 1) * 64;
    const int fr = lane & 15;
    const int fq = (lane >> 4) * 8;
    f32x4 acc[4][4] = {};
    for (int k0 = 0; k0 < Kd; k0 += 32) {
        glds16(Ag0 + k0, Al0);
        glds16(Ag1 + k0, Al1);
        glds16(Wp0 + k0, Bl0);
        glds16(Wp1 + k0, Bl1);
        __syncthreads();
        hfrag af[4], bf[4];
        #pragma unroll
        for (int i = 0; i < 4; ++i)
            af[i] = *(const hfrag*)(As + (wr + i*16 + fr)*32 + fq);
        #pragma unroll
        for (int j = 0; j < 4; ++j)
            bf[j] = *(const hfrag*)(Bs + (wc + j*16 + fr)*32 + fq);
        #pragma unroll
        for (int i = 0; i < 4; ++i)
            #pragma unroll
            for (int j = 0; j < 4; ++j)
                acc[i][j] = __builtin_amdgcn_mfma_f32_16x16x32_f16(af[i], bf[j], acc[i][j], 0, 0, 0);
        __syncthreads();
    }
    #pragma unroll
    for (int i = 0; i < 4; ++i) {
        const int row = m0 + wr + i*16 + (lane >> 4)*4;
        float rm[4];
        if (EPI == 1) {
            #pragma unroll
            for (int r = 0; r < 4; ++r) rm[r] = rowmask[row + r];
        }
        #pragma unroll
        for (int j = 0; j < 4; ++j) {
            const int col = n0 + wc + j*16 + (lane & 15);
            float bv = (EPI == 2 || EPI == 3) ? bias[col] : 0.f;
            #pragma unroll
            for (int r = 0; r < 4; ++r) {
                float v = acc[i][j][r];
                if (EPI == 1) v *= rm[r];
                if (EPI == 2) { v += bv; v = 0.5f * v * (1.f + erff(v * 0.70710678118654752f)); }
                if (EPI == 3) { v += bv; v = 1.f / (1.f + expf(-v)); }
                if (OUTH) ((unsigned short*)Cv)[(size_t)(row + r) * N + col] = f2h(v);
                else      ((float*)Cv)[(size_t)(row + r) * N + col] = v;
            }
        }
    }
}

// ---------------------------------------------------------------------------
// Per-(b,l) attention over K=4 states, fp16 q/k/v, fp32 math in LDS.
__global__ __launch_bounds__(256) void attn_kernel(
        unsigned short* Qb /* in: q, out: attn_out */,
        const unsigned short* __restrict__ Kb, const unsigned short* __restrict__ Vb,
        const float* __restrict__ nsw, const float* __restrict__ rowmask,
        float* __restrict__ attn_mean_out) {
    __shared__ float qs[KK][DD];
    __shared__ float ksm[KK][DD];
    __shared__ float vs[KK][DD];
    __shared__ float att[128];           // [h*16 + i*4 + j]
    __shared__ float lw[KK], mk[KK];
    int bl = blockIdx.x, b = bl >> 10, mb = bl * KK;
    int tid = threadIdx.x;
    const ushort4* q4 = (const ushort4*)(Qb + (size_t)mb*DD);
    const ushort4* k4 = (const ushort4*)(Kb + (size_t)mb*DD);
    const ushort4* v4 = (const ushort4*)(Vb + (size_t)mb*DD);
    #pragma unroll
    for (int p = 0; p < 2; ++p) {
        int idx = p*256 + tid;           // 0..511 ushort4 covering 4x512 elems
        int k = idx >> 7, dd = (idx & 127) << 2;
        ushort4 a = q4[idx];
        qs[k][dd] = h2f(a.x); qs[k][dd+1] = h2f(a.y); qs[k][dd+2] = h2f(a.z); qs[k][dd+3] = h2f(a.w);
        ushort4 c = k4[idx];
        ksm[k][dd] = h2f(c.x); ksm[k][dd+1] = h2f(c.y); ksm[k][dd+2] = h2f(c.z); ksm[k][dd+3] = h2f(c.w);
        ushort4 e = v4[idx];
        vs[k][dd] = h2f(e.x); vs[k][dd+1] = h2f(e.y); vs[k][dd+2] = h2f(e.z); vs[k][dd+3] = h2f(e.w);
    }
    if (tid < KK) {
        lw[tid] = logf(fmaxf(nsw[b*KK + tid], EPSF));
        mk[tid] = rowmask[mb + tid];
    }
    __syncthreads();
    if (tid < 128) {
        int h = tid >> 4, i = (tid >> 2) & 3, j = tid & 3;
        float s = 0.f;
        #pragma unroll 16
        for (int d = 0; d < HD; ++d) s = fmaf(qs[i][h*HD + d], ksm[j][h*HD + d], s);
        float lg = s * SCALE + lw[j];
        att[tid] = (mk[j] > 0.5f) ? lg : -INFINITY;
    }
    __syncthreads();
    if (tid < 32) {
        int base = tid * 4;
        float l0 = att[base], l1 = att[base+1], l2 = att[base+2], l3 = att[base+3];
        float m = fmaxf(fmaxf(l0, l1), fmaxf(l2, l3));
        if (m == -INFINITY) {
            att[base] = att[base+1] = att[base+2] = att[base+3] = 0.f;
        } else {
            float e0 = expf(l0 - m), e1 = expf(l1 - m), e2 = expf(l2 - m), e3 = expf(l3 - m);
            float inv = 1.f / (e0 + e1 + e2 + e3);
            att[base] = e0*inv; att[base+1] = e1*inv; att[base+2] = e2*inv; att[base+3] = e3*inv;
        }
    }
    __syncthreads();
    if (tid < KK) {
        float s = 0.f;
        for (int hi = 0; hi < 32; ++hi) s += att[hi*4 + tid];
        attn_mean_out[(size_t)bl*KK + tid] = s * (1.f/32.f);
    }
    float outv[8];
    #pragma unroll
    for (int p = 0; p < 8; ++p) {
        int idx = p*256 + tid;
        int i = idx >> 9, dc = idx & 511, h = dc >> 6;
        float s = 0.f;
        #pragma unroll
        for (int j = 0; j < KK; ++j) s = fmaf(att[h*16 + i*4 + j], vs[j][dc], s);
        outv[p] = s;
    }
    #pragma unroll
    for (int p = 0; p < 8; ++p) {
        int idx = p*256 + tid;
        int i = idx >> 9, dc = idx & 511;
        Qb[(size_t)(mb+i)*DD + dc] = f2h(outv[p]);
    }
}

// ---------------------------------------------------------------------------
__device__ __forceinline__ void block_reduce2(float& a, float& b, float* lds) {
    #pragma unroll
    for (int o = 32; o > 0; o >>= 1) {
        a += __shfl_down(a, o, 64);
        b += __shfl_down(b, o, 64);
    }
    int wave = threadIdx.x >> 6, lane = threadIdx.x & 63;
    if (lane == 0) { lds[wave*2] = a; lds[wave*2+1] = b; }
    __syncthreads();
    if (threadIdx.x == 0) {
        float sa = 0.f, sb = 0.f;
        for (int w = 0; w < 4; ++w) { sa += lds[2*w]; sb += lds[2*w+1]; }
        lds[0] = sa; lds[1] = sb;
    }
    __syncthreads();
    a = lds[0]; b = lds[1];
    __syncthreads();
}

// attn_pooled + LN1(gate_in) -> Hin (fp16); wm/mx read back from d_out (fp32).
__global__ __launch_bounds__(256) void pool_kernel(
        const unsigned short* __restrict__ AOP,
        const float* __restrict__ nsw, const float* __restrict__ rowmask,
        const float* __restrict__ in_wm, const float* __restrict__ in_mx,
        const float* __restrict__ ln1_g, const float* __restrict__ ln1_b,
        float* __restrict__ out_ap, unsigned short* __restrict__ hin) {
    __shared__ float red[16];
    int bl = blockIdx.x, b = bl >> 10, mb = bl * KK;
    int tid = threadIdx.x;
    float swr[KK]; float ssum = 0.f;
    #pragma unroll
    for (int k = 0; k < KK; ++k) {
        swr[k] = nsw[b*KK + k] * rowmask[mb + k];
        ssum += swr[k];
    }
    float inv = 1.f / fmaxf(ssum, EPSF);
    #pragma unroll
    for (int k = 0; k < KK; ++k) swr[k] *= inv;
    float apv[2], wmv[2], mxv[2];
    float lsum = 0.f, lsq = 0.f;
    #pragma unroll
    for (int it = 0; it < 2; ++it) {
        int d = tid + it*256;
        float ap = 0.f;
        #pragma unroll
        for (int k = 0; k < KK; ++k)
            ap = fmaf(h2f(AOP[(size_t)(mb+k)*DD + d]), swr[k], ap);
        float wm = in_wm[(size_t)bl*DD + d];
        float mx = in_mx[(size_t)bl*DD + d];
        apv[it] = ap; wmv[it] = wm; mxv[it] = mx;
        lsum += ap + wm + mx;
        lsq  += ap*ap + wm*wm + mx*mx;
    }
    block_reduce2(lsum, lsq, red);
    float mu = lsum * (1.f/(float)D3);
    float var = lsq * (1.f/(float)D3) - mu*mu;
    float rstd = rsqrtf(var + LN_EPSF);
    #pragma unroll
    for (int it = 0; it < 2; ++it) {
        int d = tid + it*256;
        out_ap[(size_t)bl*DD + d] = apv[it];
        hin[(size_t)bl*D3 + d]        = f2h((apv[it]-mu)*rstd*ln1_g[d]        + ln1_b[d]);
        hin[(size_t)bl*D3 + 512 + d]  = f2h((wmv[it]-mu)*rstd*ln1_g[512 + d]  + ln1_b[512 + d]);
        hin[(size_t)bl*D3 + 1024 + d] = f2h((mxv[it]-mu)*rstd*ln1_g[1024 + d] + ln1_b[1024 + d]);
    }
}

// ---------------------------------------------------------------------------
__global__ __launch_bounds__(256) void final_kernel(
        const float* __restrict__ out_ap, const float* __restrict__ out_wm,
        const float* __restrict__ out_mx, const float* __restrict__ gate,
        const float* __restrict__ norm_g, const float* __restrict__ norm_b,
        float* __restrict__ fused) {
    __shared__ float red[16];
    int bl = blockIdx.x;
    int tid = threadIdx.x;
    float pre[2];
    float lsum = 0.f, lsq = 0.f;
    #pragma unroll
    for (int it = 0; it < 2; ++it) {
        int d = tid + it*256;
        float ap = out_ap[(size_t)bl*DD + d];
        float wm = out_wm[(size_t)bl*DD + d];
        float mx = out_mx[(size_t)bl*DD + d];
        float g  = gate[(size_t)bl*DD + d];
        float fb = 0.5f * (ap + wm);
        float p = g*fb + (1.f-g)*mx + wm;
        pre[it] = p;
        lsum += p; lsq += p*p;
    }
    block_reduce2(lsum, lsq, red);
    float mu = lsum * (1.f/(float)DD);
    float var = lsq * (1.f/(float)DD) - mu*mu;
    float rstd = rsqrtf(var + LN_EPSF);
    #pragma unroll
    for (int it = 0; it < 2; ++it) {
        int d = tid + it*256;
        fused[(size_t)bl*DD + d] = (pre[it]-mu)*rstd*norm_g[d] + norm_b[d];
    }
}

// ---------------------------------------------------------------------------
extern "C" void kernel_launch(void* const* d_in, const int* in_sizes, int n_in,
                              void* d_out, int out_size, void* d_ws, size_t ws_size,
                              hipStream_t stream) {
    const float* SR      = (const float*)d_in[0];
    const int*   residue = (const int*)d_in[1];
    const float* sw      = (const float*)d_in[2];
    const int*   roles   = (const int*)d_in[3];
    const int*   pres    = (const int*)d_in[4];
    const float* role_emb= (const float*)d_in[5];
    const float* Wq      = (const float*)d_in[6];
    const float* Wk      = (const float*)d_in[7];
    const float* Wv      = (const float*)d_in[8];
    const float* Wo      = (const float*)d_in[9];
    const float* ln1_g   = (const float*)d_in[10];
    const float* ln1_b   = (const float*)d_in[11];
    const float* Wg1     = (const float*)d_in[12];
    const float* bg1     = (const float*)d_in[13];
    const float* Wg2     = (const float*)d_in[14];
    const float* bg2     = (const float*)d_in[15];
    const float* norm_g  = (const float*)d_in[16];
    const float* norm_b  = (const float*)d_in[17];

    float* out = (float*)d_out;
    const size_t BLD = (size_t)BL * DD;
    float* f_fused = out;
    float* f_ap    = out + BLD;
    float* f_wm    = out + 2*BLD;
    float* f_mx    = out + 3*BLD;
    float* f_am    = out + 4*BLD;
    float* f_nsw   = out + 4*BLD + (size_t)BL*KK;

    char* base = (char*)d_ws;
    const size_t MD2 = (size_t)MM * DD * 2;     // 32 MB per fp16 activation buffer
    unsigned short* Xh = (unsigned short*)(base);
    unsigned short* Qh = (unsigned short*)(base + MD2);
    unsigned short* Kh = (unsigned short*)(base + 2*MD2);
    unsigned short* Vh = (unsigned short*)(base + 3*MD2);
    float*          Gate = (float*)(base + 4*MD2);                     // 16 MB
    unsigned short* Wb = (unsigned short*)(base + 4*MD2 + (size_t)BL*DD*4);  // 4 MB
    float* nsww  = (float*)(base + 4*MD2 + (size_t)BL*DD*4 + (size_t)WTOT*2);
    float* rmask = nsww + 64;
    // aliases (lifetimes verified: X dead after QKV gemms, K/V dead after attn)
    unsigned short* AOh  = Qh;   // attn_out (in-place over q)
    unsigned short* APh  = Kh;   // attn_out @ Wo^T
    unsigned short* Hin  = Vh;   // (B,L,1536) fp16
    unsigned short* Hbuf = Xh;   // gelu(h) (B,L,512) fp16
    const unsigned short* Wqh  = Wb;
    const unsigned short* Wkh  = Wb + WSZ;
    const unsigned short* Wvh  = Wb + 2*WSZ;
    const unsigned short* Woh  = Wb + 3*WSZ;
    const unsigned short* Wg1h = Wb + OG1;
    const unsigned short* Wg2h = Wb + OG2;

    dim3 blk(256);

    cvt_weights<<<WTOT/1024, blk, 0, stream>>>(Wq, Wk, Wv, Wo, Wg1, Wg2, Wb);
    nsw_kernel<<<1, 64, 0, stream>>>(sw, pres, nsww, f_nsw);
    buildx_kernel<<<(BL*128)/256, blk, 0, stream>>>(SR, residue, pres, roles, role_emb,
                                                    nsww, Xh, rmask, f_wm, f_mx);

    dim3 gBig(DD/128, MM/128);          // (4, 256)
    gemm_mfma<0,1><<<gBig, blk, 0, stream>>>(Xh, Wqh, Qh, MM, DD, DD, nullptr, nullptr);
    gemm_mfma<0,1><<<gBig, blk, 0, stream>>>(Xh, Wkh, Kh, MM, DD, DD, nullptr, nullptr);
    gemm_mfma<0,1><<<gBig, blk, 0, stream>>>(Xh, Wvh, Vh, MM, DD, DD, nullptr, nullptr);

    attn_kernel<<<BL, blk, 0, stream>>>(Qh, Kh, Vh, nsww, rmask, f_am);

    gemm_mfma<1,1><<<gBig, blk, 0, stream>>>(AOh, Woh, APh, MM, DD, DD, nullptr, rmask);

    pool_kernel<<<BL, blk, 0, stream>>>(APh, nsww, rmask, f_wm, f_mx, ln1_g, ln1_b,
                                        f_ap, Hin);

    dim3 gMlp(DD/128, BL/128);          // (4, 64)
    gemm_mfma<2,1><<<gMlp, blk, 0, stream>>>(Hin, Wg1h, Hbuf, BL, DD, D3, bg1, nullptr);
    gemm_mfma<3,0><<<gMlp, blk, 0, stream>>>(Hbuf, Wg2h, Gate, BL, DD, DD, bg2, nullptr);

    final_kernel<<<BL, blk, 0, stream>>>(f_ap, f_wm, f_mx, Gate, norm_g, norm_b, f_fused);
}

// Round 4
// 390.575 us; speedup vs baseline: 4.9943x; 1.1180x over previous
//
#include <hip/hip_runtime.h>
#include <math.h>

// Problem constants
#define BB 8
#define KK 4
#define LL 1024
#define DD 512
#define HD 64
#define D3 1536
#define MM (BB*LL*KK)   // 32768 rows for per-state GEMMs
#define BL (BB*LL)      // 8192 (b,l) positions
#define SCALE 0.125f
#define EPSF 1e-8f
#define LN_EPSF 1e-5f

typedef _Float16 hfrag __attribute__((ext_vector_type(8)));
typedef float f32x4 __attribute__((ext_vector_type(4)));

__device__ __forceinline__ unsigned short f2h(float f) {
    _Float16 h = (_Float16)f;
    unsigned short u; __builtin_memcpy(&u, &h, 2); return u;
}
__device__ __forceinline__ float h2f(unsigned short u) {
    _Float16 h; __builtin_memcpy(&h, &u, 2); return (float)h;
}

__device__ __forceinline__ void glds16(const unsigned short* g, unsigned short* l) {
    __builtin_amdgcn_global_load_lds(
        (const __attribute__((address_space(1))) void*)g,
        (__attribute__((address_space(3))) void*)l, 16, 0, 0);
}

// ---------------------------------------------------------------------------
// Fused fp32 -> fp16 weight conversion (Wq|Wk|Wv|Wo|Wg1|Wg2 concatenated)
#define WSZ 262144          // 512*512
#define OG1 1048576         // start of Wg1 (512*1536)
#define OG2 1835008         // start of Wg2
#define WTOT 2097152
__global__ __launch_bounds__(256) void cvt_weights(
        const float* __restrict__ Wq, const float* __restrict__ Wk,
        const float* __restrict__ Wv, const float* __restrict__ Wo,
        const float* __restrict__ Wg1, const float* __restrict__ Wg2,
        unsigned short* __restrict__ dst) {
    int t = blockIdx.x * 256 + threadIdx.x;   // one float4 per thread
    int e = t * 4;
    const float* src; int off;
    if      (e < WSZ)    { src = Wq;  off = e; }
    else if (e < 2*WSZ)  { src = Wk;  off = e - WSZ; }
    else if (e < 3*WSZ)  { src = Wv;  off = e - 2*WSZ; }
    else if (e < OG1)    { src = Wo;  off = e - 3*WSZ; }
    else if (e < OG2)    { src = Wg1; off = e - OG1; }
    else                 { src = Wg2; off = e - OG2; }
    float4 v = *(const float4*)(src + off);
    ushort4 o;
    o.x = f2h(v.x); o.y = f2h(v.y); o.z = f2h(v.z); o.w = f2h(v.w);
    *(ushort4*)(dst + e) = o;
}

// ---------------------------------------------------------------------------
// nsw (masks arrive as int32: harness widens numpy bool)
__global__ void nsw_kernel(const float* __restrict__ sw,
                           const int* __restrict__ pres,
                           float* __restrict__ nsw_ws, float* __restrict__ nsw_out) {
    int b = threadIdx.x;
    if (b < BB) {
        float w[KK]; float denom = 0.f, ps = 0.f;
        for (int k = 0; k < KK; ++k) {
            float p = pres[b*KK + k] ? 1.f : 0.f;
            w[k] = sw[b*KK + k] * p;
            denom += w[k]; ps += p;
        }
        for (int k = 0; k < KK; ++k) {
            float val;
            if (denom > EPSF) val = w[k] / fmaxf(denom, EPSF);
            else              val = (pres[b*KK + k] ? 1.f : 0.f) / fmaxf(ps, 1.f);
            nsw_ws[b*KK + k] = val;
            nsw_out[b*KK + k] = val;
        }
    }
}

// ---------------------------------------------------------------------------
// Build x (fp16) + weighted_mean/max_feat (fp32, exact) + rowmask.
__global__ __launch_bounds__(256) void buildx_kernel(
        const float* __restrict__ SR, const int* __restrict__ residue,
        const int* __restrict__ pres, const int* __restrict__ roles,
        const float* __restrict__ role_emb, const float* __restrict__ nsw,
        unsigned short* __restrict__ Xh, float* __restrict__ rowmask,
        float* __restrict__ out_wm, float* __restrict__ out_mx) {
    int t  = blockIdx.x * 256 + threadIdx.x;
    int bl = t >> 7;
    int d4 = (t & 127) << 2;
    int b  = bl >> 10, l = bl & 1023;
    float mk[KK], swr[KK];
    float ssum = 0.f, many = 0.f;
    #pragma unroll
    for (int k = 0; k < KK; ++k) {
        int bk = b*KK + k;
        bool valid = (residue[(size_t)bk*LL + l] != 0) && (pres[bk] != 0);
        mk[k]  = valid ? 1.f : 0.f;
        swr[k] = nsw[bk] * mk[k];
        ssum += swr[k]; many += mk[k];
    }
    float inv = 1.f / fmaxf(ssum, EPSF);
    bool hasany = many > 0.5f;
    float wmx = 0.f, wmy = 0.f, wmz = 0.f, wmw = 0.f;
    float mxx = -1e9f, mxy = -1e9f, mxz = -1e9f, mxw = -1e9f;
    #pragma unroll
    for (int k = 0; k < KK; ++k) {
        int bk = b*KK + k;
        int role = roles[bk]; if (role < 0) role = 0;
        float4 sr = *(const float4*)(SR + ((size_t)bk*LL + l)*DD + d4);
        float4 re = *(const float4*)(role_emb + (size_t)role*DD + d4);
        float xx = (sr.x + re.x)*mk[k], xy = (sr.y + re.y)*mk[k];
        float xz = (sr.z + re.z)*mk[k], xw = (sr.w + re.w)*mk[k];
        ushort4 xs; xs.x = f2h(xx); xs.y = f2h(xy); xs.z = f2h(xz); xs.w = f2h(xw);
        *(ushort4*)(Xh + (size_t)(bl*KK + k)*DD + d4) = xs;
        float s = swr[k]*inv;
        wmx = fmaf(xx, s, wmx); wmy = fmaf(xy, s, wmy);
        wmz = fmaf(xz, s, wmz); wmw = fmaf(xw, s, wmw);
        if (mk[k] > 0.5f) {
            mxx = fmaxf(mxx, xx); mxy = fmaxf(mxy, xy);
            mxz = fmaxf(mxz, xz); mxw = fmaxf(mxw, xw);
        }
    }
    if (!hasany) { mxx = mxy = mxz = mxw = 0.f; }
    float4 wmv; wmv.x = wmx; wmv.y = wmy; wmv.z = wmz; wmv.w = wmw;
    float4 mxv; mxv.x = mxx; mxv.y = mxy; mxv.z = mxz; mxv.w = mxw;
    *(float4*)(out_wm + (size_t)bl*DD + d4) = wmv;
    *(float4*)(out_mx + (size_t)bl*DD + d4) = mxv;
    if (d4 == 0) {
        #pragma unroll
        for (int k = 0; k < KK; ++k) rowmask[bl*KK + k] = mk[k];
    }
}

// ---------------------------------------------------------------------------
// MFMA GEMM: C[M,N] = A[M,K] @ W[N,K]^T, fp16 in, fp32 accum.
// TM in {128, 64} tile rows; 128 tile cols; BK=32; 4 waves.
//   TM=128: waves 2x2, each 64x64 (4x4 frags).  LDS 16 KB.
//   TM=64 : waves 2x2, each 32x64 (2x4 frags).  LDS 12 KB.
// EPI: 0=none, 1=*rowmask[m], 2=bias+gelu(exact), 3=bias+sigmoid
// OUTH: 1 = fp16 output, 0 = fp32 output
// QKVR: 1 = route output by 512-column segment into 3 consecutive (M,512)
//        buffers starting at Cv (segments never straddle a 128-col block).
template<int TM, int EPI, int OUTH, int QKVR>
__global__ __launch_bounds__(256) void gemm_mfma(
        const unsigned short* __restrict__ A, const unsigned short* __restrict__ W,
        void* __restrict__ Cv, int M, int N, int Kd,
        const float* __restrict__ bias, const float* __restrict__ rowmask) {
    constexpr int FI = TM / 32;          // frags per wave in M: 4 or 2
    __shared__ __align__(16) unsigned short As[TM*32];
    __shared__ __align__(16) unsigned short Bs[128*32];
    const int tid  = threadIdx.x;
    const int wave = tid >> 6, lane = tid & 63;
    const int m0 = blockIdx.y * TM, n0 = blockIdx.x * 128;
    const int srow = lane >> 2;          // 0..15
    const int scol = (lane & 3) << 3;    // 0,8,16,24
    // A staging: TM=128 -> 32 rows/wave (two glds16); TM=64 -> 16 rows/wave.
    const int arow = (TM == 128) ? (wave*32 + srow) : (wave*16 + srow);
    const unsigned short* Ag0 = A + (size_t)(m0 + arow) * Kd + scol;
    const unsigned short* Ag1 = Ag0 + (size_t)16 * Kd;      // TM==128 only
    unsigned short* Al0 = As + arow*32 + scol;
    unsigned short* Al1 = Al0 + 16*32;
    // B staging: 32 rows/wave always.
    const unsigned short* Wp0 = W + (size_t)(n0 + wave*32 + srow) * Kd + scol;
    const unsigned short* Wp1 = Wp0 + (size_t)16 * Kd;
    unsigned short* Bl0 = Bs + (wave*32 + srow)*32 + scol;
    unsigned short* Bl1 = Bl0 + 16*32;
    const int wr = (wave >> 1) * (TM/2);
    const int wc = (wave & 1) * 64;
    const int fr = lane & 15;
    const int fq = (lane >> 4) * 8;
    f32x4 acc[FI][4] = {};
    for (int k0 = 0; k0 < Kd; k0 += 32) {
        glds16(Ag0 + k0, Al0);
        if (TM == 128) glds16(Ag1 + k0, Al1);
        glds16(Wp0 + k0, Bl0);
        glds16(Wp1 + k0, Bl1);
        __syncthreads();
        hfrag af[FI], bf[4];
        #pragma unroll
        for (int i = 0; i < FI; ++i)
            af[i] = *(const hfrag*)(As + (wr + i*16 + fr)*32 + fq);
        #pragma unroll
        for (int j = 0; j < 4; ++j)
            bf[j] = *(const hfrag*)(Bs + (wc + j*16 + fr)*32 + fq);
        #pragma unroll
        for (int i = 0; i < FI; ++i)
            #pragma unroll
            for (int j = 0; j < 4; ++j)
                acc[i][j] = __builtin_amdgcn_mfma_f32_16x16x32_f16(af[i], bf[j], acc[i][j], 0, 0, 0);
        __syncthreads();
    }
    // Output routing for fused QKV
    unsigned short* Ch = (unsigned short*)Cv;
    int Nout = N, colbase = n0;
    if (QKVR) {
        const int seg = n0 >> 9;
        Ch = (unsigned short*)Cv + (size_t)seg * M * 512;
        Nout = 512;
        colbase = n0 - (seg << 9);
    }
    #pragma unroll
    for (int i = 0; i < FI; ++i) {
        const int row = m0 + wr + i*16 + (lane >> 4)*4;
        float rm[4];
        if (EPI == 1) {
            #pragma unroll
            for (int r = 0; r < 4; ++r) rm[r] = rowmask[row + r];
        }
        #pragma unroll
        for (int j = 0; j < 4; ++j) {
            const int col = colbase + wc + j*16 + (lane & 15);
            float bv = (EPI == 2 || EPI == 3) ? bias[col] : 0.f;
            #pragma unroll
            for (int r = 0; r < 4; ++r) {
                float v = acc[i][j][r];
                if (EPI == 1) v *= rm[r];
                if (EPI == 2) { v += bv; v = 0.5f * v * (1.f + erff(v * 0.70710678118654752f)); }
                if (EPI == 3) { v += bv; v = 1.f / (1.f + expf(-v)); }
                if (OUTH) Ch[(size_t)(row + r) * Nout + col] = f2h(v);
                else      ((float*)Cv)[(size_t)(row + r) * Nout + col] = v;
            }
        }
    }
}

// ---------------------------------------------------------------------------
// Per-(b,l) attention over K=4 states, fp16 q/k/v, fp32 math in LDS.
__global__ __launch_bounds__(256) void attn_kernel(
        unsigned short* Qb /* in: q, out: attn_out */,
        const unsigned short* __restrict__ Kb, const unsigned short* __restrict__ Vb,
        const float* __restrict__ nsw, const float* __restrict__ rowmask,
        float* __restrict__ attn_mean_out) {
    __shared__ float qs[KK][DD];
    __shared__ float ksm[KK][DD];
    __shared__ float vs[KK][DD];
    __shared__ float att[128];           // [h*16 + i*4 + j]
    __shared__ float lw[KK], mk[KK];
    int bl = blockIdx.x, b = bl >> 10, mb = bl * KK;
    int tid = threadIdx.x;
    const ushort4* q4 = (const ushort4*)(Qb + (size_t)mb*DD);
    const ushort4* k4 = (const ushort4*)(Kb + (size_t)mb*DD);
    const ushort4* v4 = (const ushort4*)(Vb + (size_t)mb*DD);
    #pragma unroll
    for (int p = 0; p < 2; ++p) {
        int idx = p*256 + tid;
        int k = idx >> 7, dd = (idx & 127) << 2;
        ushort4 a = q4[idx];
        qs[k][dd] = h2f(a.x); qs[k][dd+1] = h2f(a.y); qs[k][dd+2] = h2f(a.z); qs[k][dd+3] = h2f(a.w);
        ushort4 c = k4[idx];
        ksm[k][dd] = h2f(c.x); ksm[k][dd+1] = h2f(c.y); ksm[k][dd+2] = h2f(c.z); ksm[k][dd+3] = h2f(c.w);
        ushort4 e = v4[idx];
        vs[k][dd] = h2f(e.x); vs[k][dd+1] = h2f(e.y); vs[k][dd+2] = h2f(e.z); vs[k][dd+3] = h2f(e.w);
    }
    if (tid < KK) {
        lw[tid] = logf(fmaxf(nsw[b*KK + tid], EPSF));
        mk[tid] = rowmask[mb + tid];
    }
    __syncthreads();
    if (tid < 128) {
        int h = tid >> 4, i = (tid >> 2) & 3, j = tid & 3;
        float s = 0.f;
        #pragma unroll 16
        for (int d = 0; d < HD; ++d) s = fmaf(qs[i][h*HD + d], ksm[j][h*HD + d], s);
        float lg = s * SCALE + lw[j];
        att[tid] = (mk[j] > 0.5f) ? lg : -INFINITY;
    }
    __syncthreads();
    if (tid < 32) {
        int base = tid * 4;
        float l0 = att[base], l1 = att[base+1], l2 = att[base+2], l3 = att[base+3];
        float m = fmaxf(fmaxf(l0, l1), fmaxf(l2, l3));
        if (m == -INFINITY) {
            att[base] = att[base+1] = att[base+2] = att[base+3] = 0.f;
        } else {
            float e0 = expf(l0 - m), e1 = expf(l1 - m), e2 = expf(l2 - m), e3 = expf(l3 - m);
            float inv = 1.f / (e0 + e1 + e2 + e3);
            att[base] = e0*inv; att[base+1] = e1*inv; att[base+2] = e2*inv; att[base+3] = e3*inv;
        }
    }
    __syncthreads();
    if (tid < KK) {
        float s = 0.f;
        for (int hi = 0; hi < 32; ++hi) s += att[hi*4 + tid];
        attn_mean_out[(size_t)bl*KK + tid] = s * (1.f/32.f);
    }
    float outv[8];
    #pragma unroll
    for (int p = 0; p < 8; ++p) {
        int idx = p*256 + tid;
        int i = idx >> 9, dc = idx & 511, h = dc >> 6;
        float s = 0.f;
        #pragma unroll
        for (int j = 0; j < KK; ++j) s = fmaf(att[h*16 + i*4 + j], vs[j][dc], s);
        outv[p] = s;
    }
    #pragma unroll
    for (int p = 0; p < 8; ++p) {
        int idx = p*256 + tid;
        int i = idx >> 9, dc = idx & 511;
        Qb[(size_t)(mb+i)*DD + dc] = f2h(outv[p]);
    }
}

// ---------------------------------------------------------------------------
__device__ __forceinline__ void block_reduce2(float& a, float& b, float* lds) {
    #pragma unroll
    for (int o = 32; o > 0; o >>= 1) {
        a += __shfl_down(a, o, 64);
        b += __shfl_down(b, o, 64);
    }
    int wave = threadIdx.x >> 6, lane = threadIdx.x & 63;
    if (lane == 0) { lds[wave*2] = a; lds[wave*2+1] = b; }
    __syncthreads();
    if (threadIdx.x == 0) {
        float sa = 0.f, sb = 0.f;
        for (int w = 0; w < 4; ++w) { sa += lds[2*w]; sb += lds[2*w+1]; }
        lds[0] = sa; lds[1] = sb;
    }
    __syncthreads();
    a = lds[0]; b = lds[1];
    __syncthreads();
}

// attn_pooled + LN1(gate_in) -> Hin (fp16); wm/mx read back from d_out (fp32).
__global__ __launch_bounds__(256) void pool_kernel(
        const unsigned short* __restrict__ AOP,
        const float* __restrict__ nsw, const float* __restrict__ rowmask,
        const float* __restrict__ in_wm, const float* __restrict__ in_mx,
        const float* __restrict__ ln1_g, const float* __restrict__ ln1_b,
        float* __restrict__ out_ap, unsigned short* __restrict__ hin) {
    __shared__ float red[16];
    int bl = blockIdx.x, b = bl >> 10, mb = bl * KK;
    int tid = threadIdx.x;
    float swr[KK]; float ssum = 0.f;
    #pragma unroll
    for (int k = 0; k < KK; ++k) {
        swr[k] = nsw[b*KK + k] * rowmask[mb + k];
        ssum += swr[k];
    }
    float inv = 1.f / fmaxf(ssum, EPSF);
    #pragma unroll
    for (int k = 0; k < KK; ++k) swr[k] *= inv;
    float apv[2], wmv[2], mxv[2];
    float lsum = 0.f, lsq = 0.f;
    #pragma unroll
    for (int it = 0; it < 2; ++it) {
        int d = tid + it*256;
        float ap = 0.f;
        #pragma unroll
        for (int k = 0; k < KK; ++k)
            ap = fmaf(h2f(AOP[(size_t)(mb+k)*DD + d]), swr[k], ap);
        float wm = in_wm[(size_t)bl*DD + d];
        float mx = in_mx[(size_t)bl*DD + d];
        apv[it] = ap; wmv[it] = wm; mxv[it] = mx;
        lsum += ap + wm + mx;
        lsq  += ap*ap + wm*wm + mx*mx;
    }
    block_reduce2(lsum, lsq, red);
    float mu = lsum * (1.f/(float)D3);
    float var = lsq * (1.f/(float)D3) - mu*mu;
    float rstd = rsqrtf(var + LN_EPSF);
    #pragma unroll
    for (int it = 0; it < 2; ++it) {
        int d = tid + it*256;
        out_ap[(size_t)bl*DD + d] = apv[it];
        hin[(size_t)bl*D3 + d]        = f2h((apv[it]-mu)*rstd*ln1_g[d]        + ln1_b[d]);
        hin[(size_t)bl*D3 + 512 + d]  = f2h((wmv[it]-mu)*rstd*ln1_g[512 + d]  + ln1_b[512 + d]);
        hin[(size_t)bl*D3 + 1024 + d] = f2h((mxv[it]-mu)*rstd*ln1_g[1024 + d] + ln1_b[1024 + d]);
    }
}

// ---------------------------------------------------------------------------
__global__ __launch_bounds__(256) void final_kernel(
        const float* __restrict__ out_ap, const float* __restrict__ out_wm,
        const float* __restrict__ out_mx, const float* __restrict__ gate,
        const float* __restrict__ norm_g, const float* __restrict__ norm_b,
        float* __restrict__ fused) {
    __shared__ float red[16];
    int bl = blockIdx.x;
    int tid = threadIdx.x;
    float pre[2];
    float lsum = 0.f, lsq = 0.f;
    #pragma unroll
    for (int it = 0; it < 2; ++it) {
        int d = tid + it*256;
        float ap = out_ap[(size_t)bl*DD + d];
        float wm = out_wm[(size_t)bl*DD + d];
        float mx = out_mx[(size_t)bl*DD + d];
        float g  = gate[(size_t)bl*DD + d];
        float fb = 0.5f * (ap + wm);
        float p = g*fb + (1.f-g)*mx + wm;
        pre[it] = p;
        lsum += p; lsq += p*p;
    }
    block_reduce2(lsum, lsq, red);
    float mu = lsum * (1.f/(float)DD);
    float var = lsq * (1.f/(float)DD) - mu*mu;
    float rstd = rsqrtf(var + LN_EPSF);
    #pragma unroll
    for (int it = 0; it < 2; ++it) {
        int d = tid + it*256;
        fused[(size_t)bl*DD + d] = (pre[it]-mu)*rstd*norm_g[d] + norm_b[d];
    }
}

// ---------------------------------------------------------------------------
extern "C" void kernel_launch(void* const* d_in, const int* in_sizes, int n_in,
                              void* d_out, int out_size, void* d_ws, size_t ws_size,
                              hipStream_t stream) {
    const float* SR      = (const float*)d_in[0];
    const int*   residue = (const int*)d_in[1];
    const float* sw      = (const float*)d_in[2];
    const int*   roles   = (const int*)d_in[3];
    const int*   pres    = (const int*)d_in[4];
    const float* role_emb= (const float*)d_in[5];
    const float* Wq      = (const float*)d_in[6];
    const float* Wk      = (const float*)d_in[7];
    const float* Wv      = (const float*)d_in[8];
    const float* Wo      = (const float*)d_in[9];
    const float* ln1_g   = (const float*)d_in[10];
    const float* ln1_b   = (const float*)d_in[11];
    const float* Wg1     = (const float*)d_in[12];
    const float* bg1     = (const float*)d_in[13];
    const float* Wg2     = (const float*)d_in[14];
    const float* bg2     = (const float*)d_in[15];
    const float* norm_g  = (const float*)d_in[16];
    const float* norm_b  = (const float*)d_in[17];

    float* out = (float*)d_out;
    const size_t BLD = (size_t)BL * DD;
    float* f_fused = out;
    float* f_ap    = out + BLD;
    float* f_wm    = out + 2*BLD;
    float* f_mx    = out + 3*BLD;
    float* f_am    = out + 4*BLD;
    float* f_nsw   = out + 4*BLD + (size_t)BL*KK;

    char* base = (char*)d_ws;
    const size_t MD2 = (size_t)MM * DD * 2;     // 32 MB per fp16 activation buffer
    unsigned short* Xh = (unsigned short*)(base);
    unsigned short* Qh = (unsigned short*)(base + MD2);       // Q|K|V contiguous:
    unsigned short* Kh = (unsigned short*)(base + 2*MD2);     //  QKV routing relies
    unsigned short* Vh = (unsigned short*)(base + 3*MD2);     //  on this layout
    float*          Gate = (float*)(base + 4*MD2);                     // 16 MB
    unsigned short* Wb = (unsigned short*)(base + 4*MD2 + (size_t)BL*DD*4);  // 4 MB
    float* nsww  = (float*)(base + 4*MD2 + (size_t)BL*DD*4 + (size_t)WTOT*2);
    float* rmask = nsww + 64;
    unsigned short* AOh  = Qh;   // attn_out (in-place over q)
    unsigned short* APh  = Kh;   // attn_out @ Wo^T
    unsigned short* Hin  = Vh;   // (B,L,1536) fp16
    unsigned short* Hbuf = Xh;   // gelu(h) (B,L,512) fp16
    const unsigned short* Wqkv = Wb;            // (1536, 512) = [Wq;Wk;Wv]
    const unsigned short* Woh  = Wb + 3*WSZ;
    const unsigned short* Wg1h = Wb + OG1;
    const unsigned short* Wg2h = Wb + OG2;

    dim3 blk(256);

    cvt_weights<<<WTOT/1024, blk, 0, stream>>>(Wq, Wk, Wv, Wo, Wg1, Wg2, Wb);
    nsw_kernel<<<1, 64, 0, stream>>>(sw, pres, nsww, f_nsw);
    buildx_kernel<<<(BL*128)/256, blk, 0, stream>>>(SR, residue, pres, roles, role_emb,
                                                    nsww, Xh, rmask, f_wm, f_mx);

    // Fused QKV: C[32768,1536] routed into Qh/Kh/Vh.  Grid (12,256)=3072 blocks.
    gemm_mfma<128,0,1,1><<<dim3(12, MM/128), blk, 0, stream>>>(
        Xh, Wqkv, Qh, MM, 1536, DD, nullptr, nullptr);

    attn_kernel<<<BL, blk, 0, stream>>>(Qh, Kh, Vh, nsww, rmask, f_am);

    // Wo: kept at 128x128 (controlled A/B vs fused-QKV occupancy).
    gemm_mfma<128,1,1,0><<<dim3(4, MM/128), blk, 0, stream>>>(
        AOh, Woh, APh, MM, DD, DD, nullptr, rmask);

    pool_kernel<<<BL, blk, 0, stream>>>(APh, nsww, rmask, f_wm, f_mx, ln1_g, ln1_b,
                                        f_ap, Hin);

    // MLP: TM=64 tiles -> 512 blocks each.
    gemm_mfma<64,2,1,0><<<dim3(4, BL/64), blk, 0, stream>>>(
        Hin, Wg1h, Hbuf, BL, DD, D3, bg1, nullptr);
    gemm_mfma<64,3,0,0><<<dim3(4, BL/64), blk, 0, stream>>>(
        Hbuf, Wg2h, Gate, BL, DD, DD, bg2, nullptr);

    final_kernel<<<BL, blk, 0, stream>>>(f_ap, f_wm, f_mx, Gate, norm_g, norm_b, f_fused);
}